// Round 1
// baseline (1024.430 us; speedup 1.0000x reference)
//
#include <hip/hip_runtime.h>
#include <hip/hip_bf16.h>

#define N_NODES 12288
#define IN_DIM 256
#define OUT_DIM 128
#define NEG 0.01f
#define LOG2E 1.44269504088896340736f
#define NSPLIT 4
#define JSPAN (N_NODES / NSPLIT)     // 3072
#define ROWS_PER_BLK 64
#define TILE_J 32
#define NTILES (JSPAN / TILE_J)      // 96

typedef __attribute__((ext_vector_type(8))) short short8;
typedef __attribute__((ext_vector_type(4))) float f32x4;

__device__ __forceinline__ float fast_exp2(float x) {
#if __has_builtin(__builtin_amdgcn_exp2f)
  return __builtin_amdgcn_exp2f(x);
#else
  return exp2f(x);
#endif
}

// RNE float->bf16 (inputs always finite here)
__device__ __forceinline__ unsigned short f2bf(float x) {
  unsigned u = __float_as_uint(x);
  unsigned r = (u + 0x7FFFu + ((u >> 16) & 1u)) >> 16;
  return (unsigned short)r;
}

// ---------------- k1: nf = X @ W^T + b (fp32), also write Vt = bf16(nf)^T ----
__global__ __launch_bounds__(256) void k1_proj(
    const float* __restrict__ X, const float* __restrict__ W,
    const float* __restrict__ bias, float* __restrict__ nf,
    unsigned short* __restrict__ Vt) {
  __shared__ float Xs[32][40];    // [k][row], padded to 160B rows
  __shared__ float Ws[32][136];   // [k][col], padded to 544B rows
  const int t = threadIdx.x;
  const int i0 = blockIdx.x * 32;
  const int tx = t & 31, ty = t >> 5;   // cols 4tx.., rows 4ty..
  float acc[4][4] = {};
  for (int k0 = 0; k0 < IN_DIM; k0 += 32) {
    __syncthreads();
    {
      int r = t >> 3, kq = (t & 7) * 4;
      float4 xv = *(const float4*)&X[(size_t)(i0 + r) * IN_DIM + k0 + kq];
      Xs[kq + 0][r] = xv.x; Xs[kq + 1][r] = xv.y;
      Xs[kq + 2][r] = xv.z; Xs[kq + 3][r] = xv.w;
    }
#pragma unroll
    for (int q = 0; q < 4; ++q) {
      int idx = t + q * 256;
      int c = idx >> 3, kq = (idx & 7) * 4;
      float4 wv = *(const float4*)&W[(size_t)c * IN_DIM + k0 + kq];
      Ws[kq + 0][c] = wv.x; Ws[kq + 1][c] = wv.y;
      Ws[kq + 2][c] = wv.z; Ws[kq + 3][c] = wv.w;
    }
    __syncthreads();
#pragma unroll
    for (int kk = 0; kk < 32; ++kk) {
      float4 a = *(const float4*)&Xs[kk][ty * 4];
      float4 bv = *(const float4*)&Ws[kk][tx * 4];
      float av[4] = {a.x, a.y, a.z, a.w};
      float bw[4] = {bv.x, bv.y, bv.z, bv.w};
#pragma unroll
      for (int r = 0; r < 4; ++r)
#pragma unroll
        for (int c = 0; c < 4; ++c) acc[r][c] += av[r] * bw[c];
    }
  }
  float4 bv = *(const float4*)&bias[tx * 4];
  float bb[4] = {bv.x, bv.y, bv.z, bv.w};
#pragma unroll
  for (int r = 0; r < 4; ++r) {
    int i = i0 + ty * 4 + r;
    float o[4];
#pragma unroll
    for (int c = 0; c < 4; ++c) {
      o[c] = acc[r][c] + bb[c];
      Vt[(size_t)(tx * 4 + c) * N_NODES + i] = f2bf(o[c]);
    }
    *(float4*)&nf[(size_t)i * OUT_DIM + tx * 4] = *(float4*)o;
  }
}

// ---------------- k2: f = nf@phi1, s = nf@phi2, smax key ---------------------
__global__ __launch_bounds__(64) void k2_fs(
    const float* __restrict__ nf, const float* __restrict__ phi,
    float* __restrict__ f, float* __restrict__ s, unsigned* __restrict__ smax) {
  const int i = blockIdx.x, l = threadIdx.x;
  float2 v = *(const float2*)&nf[(size_t)i * OUT_DIM + 2 * l];
  float2 p1 = *(const float2*)&phi[2 * l];
  float2 p2 = *(const float2*)&phi[OUT_DIM + 2 * l];
  float fp = v.x * p1.x + v.y * p1.y;
  float sp = v.x * p2.x + v.y * p2.y;
#pragma unroll
  for (int o = 32; o; o >>= 1) {
    fp += __shfl_xor(fp, o);
    sp += __shfl_xor(sp, o);
  }
  if (l == 0) {
    f[i] = fp; s[i] = sp;
    unsigned u = __float_as_uint(sp);
    unsigned key = (u & 0x80000000u) ? ~u : (u | 0x80000000u);
    atomicMax(smax, key);
  }
}

// ---------------- k3: fused mask/softmax-numerator + P@V (bf16 MFMA) ---------
// grid = 192 row-blocks x NSPLIT j-splits; block = 256 thr (4 waves)
// wave w owns d-slice [32w, 32w+32); P tile shared via LDS
__global__ __launch_bounds__(256) void k3_attn(
    const int* __restrict__ adj, const unsigned short* __restrict__ Vt,
    const float* __restrict__ f, const float* __restrict__ s,
    const unsigned* __restrict__ smaxk,
    float* __restrict__ pacc, float* __restrict__ pden) {
  __shared__ float s_lds[JSPAN];                        // 12 KB
  __shared__ __align__(16) unsigned short Vt_lds[128 * 40];  // 10 KB (80B rows)
  __shared__ __align__(16) unsigned short P_lds[64 * 40];    // 5 KB
  __shared__ float den_lds[64][4];
  const int t = threadIdx.x;
  const int sp = blockIdx.x & (NSPLIT - 1);
  const int rb = blockIdx.x >> 2;
  const int j0g = sp * JSPAN;
  const int i_loc = t >> 2, jg = t & 3;       // P-compute mapping
  const int i = rb * ROWS_PER_BLK + i_loc;
  // stage s slice
#pragma unroll
  for (int q = 0; q < 3; ++q) {
    int idx = (t + q * 256) * 4;
    *(float4*)&s_lds[idx] = *(const float4*)&s[j0g + idx];
  }
  unsigned key = *smaxk;
  unsigned u = (key & 0x80000000u) ? (key ^ 0x80000000u) : ~key;
  const float smaxv = __uint_as_float(u);
  const float fi = f[i];
  const float xm = fi + smaxv;
  const float m = fmaxf(xm, NEG * xm);        // m_i = lrelu(f_i + s*) >= all sims in row
  const float em = m * LOG2E;
  const int diag_loc = i - j0g;               // local diag col (may be out of range)
  float dsum = 0.f;
  f32x4 acc[4][2] = {};                       // [m-tile][n-tile]
  const int w = t >> 6, l = t & 63;
  const int slot = 8 * (l >> 4);              // k-group slot (ushorts)
  // Vt staging mapping: thread -> (row d = t>>1, 32B half h = t&1)
  const int sd = t >> 1, sh = (t & 1) * 16;
  const unsigned short* vsrc_base = Vt + (size_t)sd * N_NODES + j0g + sh;
  unsigned short* vdst = &Vt_lds[sd * 40 + sh];
  const int* adj_base = adj + (size_t)i * N_NODES + j0g + jg * 8;
  __syncthreads();  // s_lds ready
  for (int tile = 0; tile < NTILES; ++tile) {
    const int jl0 = tile * TILE_J;
    // stage Vt tile (128 x 32 bf16, padded rows)
    int4 v0 = *(const int4*)(vsrc_base + jl0);
    int4 v1 = *(const int4*)(vsrc_base + jl0 + 8);
    *(int4*)vdst = v0;
    *(int4*)(vdst + 8) = v1;
    // compute 8 p-values for (row i, js jl..jl+8)
    const int jl = jl0 + jg * 8;
    int4 a0 = *(const int4*)(adj_base + jl0);
    int4 a1 = *(const int4*)(adj_base + jl0 + 4);
    float4 sA = *(const float4*)&s_lds[jl];
    float4 sB = *(const float4*)&s_lds[jl + 4];
    const int adjv[8] = {a0.x, a0.y, a0.z, a0.w, a1.x, a1.y, a1.z, a1.w};
    const float sv[8] = {sA.x, sA.y, sA.z, sA.w, sB.x, sB.y, sB.z, sB.w};
    short8 pv;
#pragma unroll
    for (int q = 0; q < 8; ++q) {
      float x = fi + sv[q];
      float xl = fmaxf(x, NEG * x);                       // leaky_relu
      float e = fast_exp2(__builtin_fmaf(xl, LOG2E, -em));
      bool edge = (adjv[q] > 0) || ((jl + q) == diag_loc);
      float p = edge ? e : 0.f;
      dsum += p;
      pv[q] = (short)f2bf(p);
    }
    *(short8*)&P_lds[i_loc * 40 + 8 * jg] = pv;
    __syncthreads();
    // MFMA: A = P (rows i), B = Vt (cols d); wave w does d in [32w, 32w+32)
    short8 af[4];
#pragma unroll
    for (int mt = 0; mt < 4; ++mt)
      af[mt] = *(const short8*)&P_lds[(16 * mt + (l & 15)) * 40 + slot];
#pragma unroll
    for (int nt = 0; nt < 2; ++nt) {
      short8 bfr = *(const short8*)&Vt_lds[(32 * w + 16 * nt + (l & 15)) * 40 + slot];
#pragma unroll
      for (int mt = 0; mt < 4; ++mt)
        acc[mt][nt] = __builtin_amdgcn_mfma_f32_16x16x32_bf16(af[mt], bfr, acc[mt][nt], 0, 0, 0);
    }
    __syncthreads();
  }
  den_lds[i_loc][jg] = dsum;
  __syncthreads();
  if (t < 64) {
    pden[sp * N_NODES + rb * ROWS_PER_BLK + t] =
        den_lds[t][0] + den_lds[t][1] + den_lds[t][2] + den_lds[t][3];
  }
  float* pa = pacc + (size_t)sp * N_NODES * OUT_DIM;
#pragma unroll
  for (int mt = 0; mt < 4; ++mt)
#pragma unroll
    for (int nt = 0; nt < 2; ++nt)
#pragma unroll
      for (int r = 0; r < 4; ++r) {
        int ii = rb * ROWS_PER_BLK + 16 * mt + (l >> 4) * 4 + r;  // verified C/D layout
        int d = 32 * w + 16 * nt + (l & 15);
        pa[(size_t)ii * OUT_DIM + d] = acc[mt][nt][r];
      }
}

// ---------------- k4: combine partials, divide, final leaky_relu -------------
__global__ __launch_bounds__(256) void k4_comb(
    const float* __restrict__ pacc, const float* __restrict__ pden,
    float* __restrict__ out) {
  int idx = blockIdx.x * 256 + threadIdx.x;
  int i = idx >> 7;
  float v = 0.f, den = 0.f;
#pragma unroll
  for (int spp = 0; spp < NSPLIT; ++spp) {
    v += pacc[(size_t)spp * N_NODES * OUT_DIM + idx];
    den += pden[spp * N_NODES + i];
  }
  float o = v / den;
  out[idx] = fmaxf(o, NEG * o);
}

extern "C" void kernel_launch(void* const* d_in, const int* in_sizes, int n_in,
                              void* d_out, int out_size, void* d_ws, size_t ws_size,
                              hipStream_t stream) {
  const int* adj = (const int*)d_in[0];
  const float* X = (const float*)d_in[1];
  const float* W = (const float*)d_in[2];
  const float* b = (const float*)d_in[3];
  const float* phi = (const float*)d_in[4];
  float* out = (float*)d_out;
  char* ws = (char*)d_ws;
  // ws layout (bytes, all 16-aligned):
  unsigned short* Vt = (unsigned short*)(ws);            // 128*12288*2 = 3,145,728
  float* nf   = (float*)(ws + 3145728);                  // 12288*128*4 = 6,291,456
  float* fv   = (float*)(ws + 9437184);                  // 49,152
  float* sv   = (float*)(ws + 9486336);                  // 49,152
  unsigned* smax = (unsigned*)(ws + 9535488);            // 16
  float* pden = (float*)(ws + 9535504);                  // 4*12288*4 = 196,608
  float* pacc = (float*)(ws + 9732112);                  // 4*12288*128*4 = 25,165,824

  hipMemsetAsync(smax, 0, 4, stream);
  hipLaunchKernelGGL(k1_proj, dim3(N_NODES / 32), dim3(256), 0, stream, X, W, b, nf, Vt);
  hipLaunchKernelGGL(k2_fs, dim3(N_NODES), dim3(64), 0, stream, nf, phi, fv, sv, smax);
  hipLaunchKernelGGL(k3_attn, dim3((N_NODES / ROWS_PER_BLK) * NSPLIT), dim3(256), 0, stream,
                     adj, Vt, fv, sv, smax, pacc, pden);
  hipLaunchKernelGGL(k4_comb, dim3((N_NODES * OUT_DIM) / 256), dim3(256), 0, stream,
                     pacc, pden, out);
}

// Round 2
// 990.942 us; speedup vs baseline: 1.0338x; 1.0338x over previous
//
#include <hip/hip_runtime.h>
#include <hip/hip_bf16.h>

#define N_NODES 12288
#define IN_DIM 256
#define OUT_DIM 128
#define NEG 0.01f
#define LOG2E 1.44269504088896340736f
#define NSPLIT 4
#define JSPAN (N_NODES / NSPLIT)     // 3072
#define TJ 64
#define NT (JSPAN / TJ)              // 48
#define VROW 68                      // Vt_lds row stride in ushorts (64 + 4 pad)

typedef __attribute__((ext_vector_type(8))) short short8;
typedef __attribute__((ext_vector_type(4))) float f32x4;

__device__ __forceinline__ float fast_exp2(float x) {
#if __has_builtin(__builtin_amdgcn_exp2f)
  return __builtin_amdgcn_exp2f(x);
#else
  return exp2f(x);
#endif
}

// RNE float->bf16 (inputs always finite here)
__device__ __forceinline__ unsigned short f2bf(float x) {
  unsigned u = __float_as_uint(x);
  unsigned r = (u + 0x7FFFu + ((u >> 16) & 1u)) >> 16;
  return (unsigned short)r;
}

// ---------------- k1: proj + bf16 V^T + fused f/s + block-max(s) -------------
// nf = X@W^T + b computed in registers; Vt = bf16(nf)^T written; f = nf@phi1,
// s = nf@phi2 reduced across col-lanes; one atomicMax per block (384 total).
__global__ __launch_bounds__(256) void k1_proj(
    const float* __restrict__ X, const float* __restrict__ W,
    const float* __restrict__ bias, const float* __restrict__ phi,
    unsigned short* __restrict__ Vt, float* __restrict__ f,
    float* __restrict__ s, unsigned* __restrict__ smax) {
  __shared__ float Xs[32][40];    // [k][row]
  __shared__ float Ws[32][136];   // [k][col]
  __shared__ unsigned skey[8];
  const int t = threadIdx.x;
  const int i0 = blockIdx.x * 32;
  const int tx = t & 31, ty = t >> 5;   // cols 4tx.., rows 4ty..
  float acc[4][4] = {};
  for (int k0 = 0; k0 < IN_DIM; k0 += 32) {
    __syncthreads();
    {
      int r = t >> 3, kq = (t & 7) * 4;
      float4 xv = *(const float4*)&X[(size_t)(i0 + r) * IN_DIM + k0 + kq];
      Xs[kq + 0][r] = xv.x; Xs[kq + 1][r] = xv.y;
      Xs[kq + 2][r] = xv.z; Xs[kq + 3][r] = xv.w;
    }
#pragma unroll
    for (int q = 0; q < 4; ++q) {
      int idx = t + q * 256;
      int c = idx >> 3, kq = (idx & 7) * 4;
      float4 wv = *(const float4*)&W[(size_t)c * IN_DIM + k0 + kq];
      Ws[kq + 0][c] = wv.x; Ws[kq + 1][c] = wv.y;
      Ws[kq + 2][c] = wv.z; Ws[kq + 3][c] = wv.w;
    }
    __syncthreads();
#pragma unroll
    for (int kk = 0; kk < 32; ++kk) {
      float4 a = *(const float4*)&Xs[kk][ty * 4];
      float4 bv = *(const float4*)&Ws[kk][tx * 4];
      float av[4] = {a.x, a.y, a.z, a.w};
      float bw[4] = {bv.x, bv.y, bv.z, bv.w};
#pragma unroll
      for (int r = 0; r < 4; ++r)
#pragma unroll
        for (int c = 0; c < 4; ++c) acc[r][c] += av[r] * bw[c];
    }
  }
  float4 bv = *(const float4*)&bias[tx * 4];
  float bb[4] = {bv.x, bv.y, bv.z, bv.w};
  float4 p1 = *(const float4*)&phi[tx * 4];
  float4 p2 = *(const float4*)&phi[OUT_DIM + tx * 4];
  float p1a[4] = {p1.x, p1.y, p1.z, p1.w};
  float p2a[4] = {p2.x, p2.y, p2.z, p2.w};
  float fp[4], sp_[4];
#pragma unroll
  for (int r = 0; r < 4; ++r) {
    int i = i0 + ty * 4 + r;
    float o[4];
    fp[r] = 0.f; sp_[r] = 0.f;
#pragma unroll
    for (int c = 0; c < 4; ++c) {
      o[c] = acc[r][c] + bb[c];
      Vt[(size_t)(tx * 4 + c) * N_NODES + i] = f2bf(o[c]);
      fp[r] = __builtin_fmaf(o[c], p1a[c], fp[r]);
      sp_[r] = __builtin_fmaf(o[c], p2a[c], sp_[r]);
    }
  }
#pragma unroll
  for (int o = 16; o; o >>= 1) {
#pragma unroll
    for (int r = 0; r < 4; ++r) {
      fp[r] += __shfl_xor(fp[r], o);
      sp_[r] += __shfl_xor(sp_[r], o);
    }
  }
  if (tx == 0) {
    unsigned kmax = 0;
#pragma unroll
    for (int r = 0; r < 4; ++r) {
      int i = i0 + ty * 4 + r;
      f[i] = fp[r]; s[i] = sp_[r];
      unsigned u = __float_as_uint(sp_[r]);
      unsigned key = (u & 0x80000000u) ? ~u : (u | 0x80000000u);
      kmax = max(kmax, key);
    }
    skey[ty] = kmax;
  }
  __syncthreads();
  if (t == 0) {
    unsigned kmax = skey[0];
#pragma unroll
    for (int q = 1; q < 8; ++q) kmax = max(kmax, skey[q]);
    atomicMax(smax, kmax);
  }
}

// ---------------- k3: fused mask/softmax-numerator + P@V (bf16 MFMA) ---------
// grid = 192 row-blocks x NSPLIT j-splits; block = 256 thr (4 waves)
// wave w owns rows [16w,16w+16); P computed in-register in A-frag layout.
// Double-buffered Vt LDS, distance-2 adj register prefetch, raw barrier
// (lgkmcnt(0) only -> adj loads stay in flight across barriers).
__global__ __launch_bounds__(256, 3) void k3_attn(
    const int* __restrict__ adj, const unsigned short* __restrict__ Vt,
    const float* __restrict__ f, const float* __restrict__ s,
    const unsigned* __restrict__ smaxk,
    float* __restrict__ pacc, float* __restrict__ pden) {
  __shared__ float s_lds[JSPAN];                                 // 12 KB
  __shared__ __align__(16) unsigned short Vt_lds[2][128 * VROW]; // 34 KB
  const int t = threadIdx.x;
  const int sp = blockIdx.x & (NSPLIT - 1);
  const int rb = blockIdx.x >> 2;
  const int j0g = sp * JSPAN;
  const int w = t >> 6, l = t & 63;
  const int m = l & 15, slot = l >> 4;
  const int row_g = rb * 64 + w * 16 + m;     // P row this lane computes
  // stage s slice
#pragma unroll
  for (int q = 0; q < 3; ++q) {
    int idx = (t + q * 256) * 4;
    *(float4*)&s_lds[idx] = *(const float4*)&s[j0g + idx];
  }
  unsigned key = *smaxk;
  unsigned ku = (key & 0x80000000u) ? (key ^ 0x80000000u) : ~key;
  const float smaxv = __uint_as_float(ku);
  const float fi = f[row_g];
  const float xm = fi + smaxv;
  const float mrow = fmaxf(xm, NEG * xm);     // >= all sims in row (monotone lrelu)
  const float em = mrow * LOG2E;
  const int diag_g = row_g - j0g;             // local self-loop col (may be OOR)
  float dsum = 0.f;
  f32x4 acc[8] = {};                          // nt = 0..7 (full d=128 per wave)
  const int* adjp = adj + (size_t)row_g * N_NODES + j0g + 8 * slot;
  const int sd = t >> 1, sh = (t & 1) * 32;   // Vt staging: row sd, 64B half
  const unsigned short* vsrc = Vt + (size_t)sd * N_NODES + j0g + sh;
  unsigned short* vd0 = &Vt_lds[0][sd * VROW + sh];
  unsigned short* vd1 = &Vt_lds[1][sd * VROW + sh];
  int4 aA[4], aB[4], aC[4], vr[4];

#define ADJ_LOAD(SET, TT) { int _o = (TT) * TJ;                       \
    SET[0] = *(const int4*)(adjp + _o);                               \
    SET[1] = *(const int4*)(adjp + _o + 4);                           \
    SET[2] = *(const int4*)(adjp + _o + 32);                          \
    SET[3] = *(const int4*)(adjp + _o + 36); }
#define VT_LOAD(TT) { int _o = (TT) * TJ;                             \
    vr[0] = *(const int4*)(vsrc + _o);                                \
    vr[1] = *(const int4*)(vsrc + _o + 8);                            \
    vr[2] = *(const int4*)(vsrc + _o + 16);                           \
    vr[3] = *(const int4*)(vsrc + _o + 24); }
#define VT_WRITE(DST) { *(int4*)(DST) = vr[0]; *(int4*)((DST) + 8) = vr[1]; \
    *(int4*)((DST) + 16) = vr[2]; *(int4*)((DST) + 24) = vr[3]; }

  // prologue: Vt(0) staged, adj(0),adj(1) in flight/regs
  VT_LOAD(0);
  ADJ_LOAD(aA, 0);
  ADJ_LOAD(aB, 1);
  VT_WRITE(vd0);
  __syncthreads();   // full drain once (also covers s_lds staging)
  int cur = 0;

#define ITER(TT, CURSET, PFSET) {                                           \
    int _tn = ((TT) + 1 < NT) ? (TT) + 1 : NT - 1;                          \
    VT_LOAD(_tn);                          /* issue first: counted wait */  \
    int _tp = ((TT) + 2 < NT) ? (TT) + 2 : NT - 1;                          \
    ADJ_LOAD(PFSET, _tp);                  /* stays in flight over barrier */\
    short8 af0, af1;                                                        \
    _Pragma("unroll")                                                       \
    for (int c = 0; c < 2; ++c) {                                           \
      int jb = (TT) * TJ + 32 * c + 8 * slot;                               \
      float4 sv0 = *(const float4*)&s_lds[jb];                              \
      float4 sv1 = *(const float4*)&s_lds[jb + 4];                          \
      int av[8] = {CURSET[2*c].x, CURSET[2*c].y, CURSET[2*c].z, CURSET[2*c].w, \
                   CURSET[2*c+1].x, CURSET[2*c+1].y, CURSET[2*c+1].z, CURSET[2*c+1].w}; \
      float sva[8] = {sv0.x, sv0.y, sv0.z, sv0.w, sv1.x, sv1.y, sv1.z, sv1.w}; \
      _Pragma("unroll")                                                     \
      for (int q = 0; q < 8; ++q) {                                         \
        float x = fi + sva[q];                                              \
        float xl = fmaxf(x, NEG * x);                                       \
        float e = fast_exp2(__builtin_fmaf(xl, LOG2E, -em));                \
        bool edge = (av[q] > 0) || ((jb + q) == diag_g);                    \
        float p = edge ? e : 0.f;                                           \
        dsum += p;                                                          \
        if (c == 0) af0[q] = (short)f2bf(p); else af1[q] = (short)f2bf(p);  \
      }                                                                     \
    }                                                                       \
    const unsigned short* vb = &Vt_lds[cur][0];                             \
    _Pragma("unroll")                                                       \
    for (int nt = 0; nt < 8; ++nt) {                                        \
      short8 b0 = *(const short8*)(vb + (nt * 16 + m) * VROW + 8 * slot);   \
      acc[nt] = __builtin_amdgcn_mfma_f32_16x16x32_bf16(af0, b0, acc[nt], 0, 0, 0); \
    }                                                                       \
    _Pragma("unroll")                                                       \
    for (int nt = 0; nt < 8; ++nt) {                                        \
      short8 b1 = *(const short8*)(vb + (nt * 16 + m) * VROW + 32 + 8 * slot); \
      acc[nt] = __builtin_amdgcn_mfma_f32_16x16x32_bf16(af1, b1, acc[nt], 0, 0, 0); \
    }                                                                       \
    unsigned short* vw = (cur ? vd0 : vd1);                                 \
    VT_WRITE(vw);                          /* compiler emits counted vmcnt */\
    asm volatile("s_waitcnt lgkmcnt(0)" ::: "memory");                      \
    __builtin_amdgcn_sched_barrier(0);                                      \
    __builtin_amdgcn_s_barrier();                                           \
    cur ^= 1; }

  for (int tb = 0; tb < NT; tb += 3) {
    ITER(tb + 0, aA, aC);
    ITER(tb + 1, aB, aA);
    ITER(tb + 2, aC, aB);
  }
#undef ITER
#undef ADJ_LOAD
#undef VT_LOAD
#undef VT_WRITE

  // row denominator: reduce over the 4 k-slot lanes {m, m+16, m+32, m+48}
  dsum += __shfl_xor(dsum, 16);
  dsum += __shfl_xor(dsum, 32);
  if (l < 16) pden[sp * N_NODES + rb * 64 + w * 16 + l] = dsum;
  // C write: out-row = rb*64 + 16w + slot*4 + r, out-col = nt*16 + m
  float* pa = pacc + (size_t)sp * N_NODES * OUT_DIM;
#pragma unroll
  for (int nt = 0; nt < 8; ++nt)
#pragma unroll
    for (int r = 0; r < 4; ++r) {
      int ii = rb * 64 + w * 16 + slot * 4 + r;
      pa[(size_t)ii * OUT_DIM + nt * 16 + m] = acc[nt][r];
    }
}

// ---------------- k4: combine partials, divide, final leaky_relu -------------
__global__ __launch_bounds__(256) void k4_comb(
    const float* __restrict__ pacc, const float* __restrict__ pden,
    float* __restrict__ out) {
  int idx = blockIdx.x * 256 + threadIdx.x;
  int i = idx >> 7;
  float v = 0.f, den = 0.f;
#pragma unroll
  for (int spp = 0; spp < NSPLIT; ++spp) {
    v += pacc[(size_t)spp * N_NODES * OUT_DIM + idx];
    den += pden[spp * N_NODES + i];
  }
  float o = v / den;
  out[idx] = fmaxf(o, NEG * o);
}

extern "C" void kernel_launch(void* const* d_in, const int* in_sizes, int n_in,
                              void* d_out, int out_size, void* d_ws, size_t ws_size,
                              hipStream_t stream) {
  const int* adj = (const int*)d_in[0];
  const float* X = (const float*)d_in[1];
  const float* W = (const float*)d_in[2];
  const float* b = (const float*)d_in[3];
  const float* phi = (const float*)d_in[4];
  float* out = (float*)d_out;
  char* ws = (char*)d_ws;
  // ws layout (bytes, 16-aligned):
  unsigned short* Vt = (unsigned short*)(ws);            // 128*12288*2 = 3,145,728
  float* fv   = (float*)(ws + 3145728);                  // 49,152
  float* sv   = (float*)(ws + 3194880);                  // 49,152
  unsigned* smax = (unsigned*)(ws + 3244032);            // 16
  float* pden = (float*)(ws + 3244048);                  // 4*12288*4 = 196,608
  float* pacc = (float*)(ws + 3440656);                  // 4*12288*128*4 = 25,165,824

  hipMemsetAsync(smax, 0, 4, stream);
  hipLaunchKernelGGL(k1_proj, dim3(N_NODES / 32), dim3(256), 0, stream,
                     X, W, b, phi, Vt, fv, sv, smax);
  hipLaunchKernelGGL(k3_attn, dim3((N_NODES / 64) * NSPLIT), dim3(256), 0, stream,
                     adj, Vt, fv, sv, smax, pacc, pden);
  hipLaunchKernelGGL(k4_comb, dim3((N_NODES * OUT_DIM) / 256), dim3(256), 0, stream,
                     pacc, pden, out);
}